// Round 1
// baseline (1570.455 us; speedup 1.0000x reference)
//
#include <hip/hip_runtime.h>
#include <math.h>

#define EPSF 1e-20f
static constexpr int N  = 32;
static constexpr int Hh = 192;
static constexpr int Ww = 192;
static constexpr int Bb = 2;
static constexpr int HW = Hh * Ww;            // 36864

// workspace layout (in floats)
static constexpr size_t OFF_WCONV_D = 0;                    // 32*32*9   = 9216
static constexpr size_t OFF_WCONV_E = 9216;                 // 128*128*9 = 147456
static constexpr size_t OFF_WPROP   = 156672;               // 32*4
static constexpr size_t OFF_WPOW    = 156800;               // 32*2*4
static constexpr size_t OFF_CE_IN   = 157056;               // 2*128*HW  = 9437184
static constexpr size_t OFF_ECE_IN  = OFF_CE_IN + (size_t)2*128*HW;
// total = 19,031,424 floats = 72.6 MiB of ws

static constexpr size_t OUT0_SZ  = (size_t)4 * N * HW;      // 4,718,592
static constexpr size_t EOUT_SZ  = (size_t)Bb * N * 4 * HW; // 9,437,184

__device__ __forceinline__ float softplusf(float x) { return log1pf(expf(x)); }
__device__ __forceinline__ float sigmf(float x)     { return 1.f / (1.f + expf(-x)); }

// ---------------------------------------------------------------- weights ---
__global__ void prep_weights(const float* __restrict__ Wcd, const float* __restrict__ Wsd,
                             const float* __restrict__ Wce, const float* __restrict__ Wse0,
                             const float* __restrict__ Wse1, const float* __restrict__ Wse3,
                             const float* __restrict__ Wdir, const float* __restrict__ Wpow,
                             const float* __restrict__ Wprop, float* __restrict__ ws)
{
    __shared__ float s_wcd[32][32];
    __shared__ float s_wce[32][32];
    __shared__ float s_wsd[32][9];
    __shared__ float s_wse[32][4][9];
    __shared__ float s_wdir[4][32][4];
    const int tid = threadIdx.x;

    // normalized channel weights (rows)
    if (tid < 64) {
        int o = tid & 31;
        const float* src = (tid < 32) ? Wcd : Wce;
        float s = 0.f;
        for (int i = 0; i < 32; ++i) s += softplusf(src[o * 32 + i]);
        float inv = 1.f / s;
        for (int i = 0; i < 32; ++i) {
            float v = softplusf(src[o * 32 + i]) * inv;
            if (tid < 32) s_wcd[o][i] = v; else s_wce[o][i] = v;
        }
    }
    // spatial_d: (N,3,2) -> symmetric (N,3,3), normalized
    if (tid < 32) {
        int i = tid;
        float c0[3], c1[3]; float s = 0.f;
        for (int h = 0; h < 3; ++h) {
            c0[h] = softplusf(Wsd[(i * 3 + h) * 2 + 0]);
            c1[h] = softplusf(Wsd[(i * 3 + h) * 2 + 1]);
            s += 2.f * c0[h] + c1[h];
        }
        float inv = 1.f / s;
        for (int h = 0; h < 3; ++h) {
            s_wsd[i][h * 3 + 0] = c0[h] * inv;
            s_wsd[i][h * 3 + 1] = c1[h] * inv;
            s_wsd[i][h * 3 + 2] = c0[h] * inv;
        }
    }
    // spatial_e per (i,d), normalized over 3x3
    if (tid < 128) {
        int i = tid >> 2, d = tid & 3;
        float v[9];
        for (int h = 0; h < 3; ++h)
            for (int w = 0; w < 3; ++w) {
                float val;
                if (d == 0)      val = softplusf(Wse0[(i * 3 + h) * 3 + w]);
                else if (d == 1) val = softplusf(Wse1[(i * 3 + h) * 2 + (w == 1 ? 1 : 0)]);
                else if (d == 2) val = softplusf(Wse0[(i * 3 + h) * 3 + (2 - w)]);
                else             val = softplusf(Wse3[(i * 3 + h) * 2 + (w == 1 ? 1 : 0)]);
                v[h * 3 + w] = val;
            }
        float s = 0.f;
        for (int k = 0; k < 9; ++k) s += v[k];
        float inv = 1.f / s;
        for (int k = 0; k < 9; ++k) s_wse[i][d][k] = v[k] * inv;
    }
    // dir weights per (p,i), normalized over d
    if (tid < 128) {
        int p = tid >> 5, i = tid & 31;
        const int jmap[4][4] = {{0,1,2,3},{4,5,4,6},{2,1,0,3},{7,8,7,9}};
        float v[4]; float s = 0.f;
        for (int d = 0; d < 4; ++d) { v[d] = softplusf(Wdir[i * 10 + jmap[p][d]]); s += v[d]; }
        float inv = 1.f / s;
        for (int d = 0; d < 4; ++d) s_wdir[p][i][d] = v[d] * inv;
    }
    // pow + prop straight to ws
    if (tid < 32) {
        int i = tid;
        float p0 = softplusf(Wpow[i*5+0]), p1 = softplusf(Wpow[i*5+1]), p2 = softplusf(Wpow[i*5+2]);
        float p3 = softplusf(Wpow[i*5+3]), p4 = softplusf(Wpow[i*5+4]);
        float* wp = ws + OFF_WPOW + (size_t)i * 8;
        wp[0]=p0; wp[1]=p2; wp[2]=p1; wp[3]=p4;   // s=0 (fwd)
        wp[4]=p1; wp[5]=p3; wp[6]=p0; wp[7]=p4;   // s=1 (bwd)
        float c0 = sigmf(Wprop[i*3+0]), c1 = sigmf(Wprop[i*3+1]), c2 = sigmf(Wprop[i*3+2]);
        float* pr = ws + OFF_WPROP + (size_t)i * 4;
        pr[0]=c1; pr[1]=c0; pr[2]=c1; pr[3]=c2;
    }
    __syncthreads();
    // w_conv_d[(o*32+i)*9+k]
    for (int idx = tid; idx < 32 * 32 * 9; idx += 256) {
        int k = idx % 9; int t = idx / 9; int i = t & 31; int o = t >> 5;
        ws[OFF_WCONV_D + idx] = s_wcd[o][i] * s_wsd[i][k];
    }
    // w_conv_e[((o*4+p)*128 + i*4+d)*9 + k]
    for (int idx = tid; idx < 128 * 128 * 9; idx += 256) {
        int k = idx % 9; int t = idx / 9; int i4 = t & 127; int o4 = t >> 7;
        int o = o4 >> 2, p = o4 & 3, i = i4 >> 2, d = i4 & 3;
        ws[OFF_WCONV_E + idx] = s_wce[o][i] * s_wdir[p][i][d] * s_wse[i][d][k];
    }
}

// -------------------------------------------------------------- ce/ece in ---
__global__ __launch_bounds__(192) void prep_inputs(
    const float* __restrict__ xin, const float* __restrict__ ce,
    const float* __restrict__ ece, const float* __restrict__ wsw,
    float* __restrict__ ce_in, float* __restrict__ ece_in)
{
    const int x = threadIdx.x;      // 0..191
    const int y = blockIdx.x;       // 0..191
    const int i = blockIdx.y;       // 0..31
    const int b = blockIdx.z;       // 0..1
    const float* dcd = xin + ((size_t)(b * N + i)) * HW;
    const float* cd  = xin + ((size_t)((Bb + b) * N + i)) * HW;

    float cdv[3][3], dv[3][3];
    #pragma unroll
    for (int dy = -1; dy <= 1; ++dy)
        #pragma unroll
        for (int dx = -1; dx <= 1; ++dx) {
            int yy = y + dy, xx = x + dx;
            bool in = (yy >= 0 && yy < Hh && xx >= 0 && xx < Ww);
            float c = in ? cd[yy * Ww + xx] : 0.f;
            float dd = in ? dcd[yy * Ww + xx] : 0.f;
            cdv[dy + 1][dx + 1] = c;
            dv[dy + 1][dx + 1] = in ? dd / (c + EPSF) : 0.f;
        }
    const float* wprop = wsw + OFF_WPROP;
    const float* wpow  = wsw + OFF_WPOW;
    const int oy[4] = {-1, -1, -1, 0}, ox[4] = {-1, 0, 1, 1};
    #pragma unroll
    for (int d = 0; d < 4; ++d) {
        float nf = dv[1 + oy[d]][1 + ox[d]];
        float df = dv[1 - oy[d]][1 - ox[d]];
        float rf = nf / (df + EPSF);
        float rb = df / (nf + EPSF);
        float p0 = wpow[i * 8 + d], p1 = wpow[i * 8 + 4 + d];
        float ef = powf(fminf(fmaxf(rf, EPSF), 1.f), p0);
        float eb = powf(fminf(fmaxf(rb, EPSF), 1.f), p1);
        float en = fminf(fmaxf(fminf(ef, eb), 0.f), 1.f);
        float cn = cdv[1 + oy[d]][1 + ox[d]] * cdv[1 - oy[d]][1 - ox[d]];
        float wp = wprop[i * 4 + d];
        size_t idx = ((size_t)(b * 128 + i * 4 + d)) * HW + (size_t)y * Ww + x;
        ce_in[idx]  = ce[idx] * wp + cn * (1.f - wp);
        ece_in[idx] = ece[idx] * wp + en * cn * (1.f - wp);
    }
}

// -------------------------------------------------- 128->128 3x3 conv (e) ---
__global__ __launch_bounds__(256) void conv_e(
    const float* __restrict__ ce_in, const float* __restrict__ ece_in,
    const float* __restrict__ wte,
    float* __restrict__ ce_out, float* __restrict__ ece_out)
{
    const int z = blockIdx.z; const int t = z >> 1; const int b = z & 1;
    const float* inp = t ? ece_in : ce_in;
    float* outp      = t ? ece_out : ce_out;
    const float* in_base = inp + (size_t)b * 128 * HW;

    __shared__ float tile[18][8][18];   // [y][ic][x] -> 2-way bank alias only (free)
    const int tid = threadIdx.x;
    const int tx = tid & 15, ty = tid >> 4;
    const int x0 = ((int)blockIdx.x % 12) * 16, y0 = ((int)blockIdx.x / 12) * 16;
    const int ocg = blockIdx.y;          // 0..3 -> output channels ocg*32..+31

    float acc[32];
    #pragma unroll
    for (int o = 0; o < 32; ++o) acc[o] = 0.f;

    for (int ch = 0; ch < 16; ++ch) {    // 16 chunks of 8 input channels
        __syncthreads();
        for (int idx = tid; idx < 18 * 8 * 18; idx += 256) {
            int xx = idx % 18; int r = idx / 18; int ic = r & 7; int yy = r >> 3;
            int gy = y0 + yy - 1, gx = x0 + xx - 1;
            float v = 0.f;
            if (gy >= 0 && gy < Hh && gx >= 0 && gx < Ww)
                v = in_base[(size_t)(ch * 8 + ic) * HW + (size_t)gy * Ww + gx];
            tile[yy][ic][xx] = v;
        }
        __syncthreads();
        for (int ic = 0; ic < 8; ++ic) {
            float v[9];
            #pragma unroll
            for (int k = 0; k < 9; ++k) v[k] = tile[ty + k / 3][ic][tx + k % 3];
            const float* wb = wte + ((size_t)(ocg * 32) * 128 + ch * 8 + ic) * 9;
            #pragma unroll
            for (int o = 0; o < 32; ++o) {
                const float* wo = wb + (size_t)o * 128 * 9;   // block-uniform -> s_load
                float a = acc[o];
                #pragma unroll
                for (int k = 0; k < 9; ++k) a += wo[k] * v[k];
                acc[o] = a;
            }
        }
    }
    #pragma unroll
    for (int o = 0; o < 32; ++o)
        outp[((size_t)b * 128 + ocg * 32 + o) * HW + (size_t)(y0 + ty) * Ww + (x0 + tx)] = acc[o];
}

// --------------------------------------- gated 32->32 conv (dcd_out/cd_out) --
__global__ __launch_bounds__(256) void conv_d(
    const float* __restrict__ xin, const float* __restrict__ wd,
    const float* __restrict__ ece_out, const float* __restrict__ ce_out,
    float* __restrict__ out0)
{
    const int b = blockIdx.y;   // 0..1
    const int t = blockIdx.z;   // 0: dcd, 1: cd
    const float* src = xin + ((size_t)(t * Bb + b)) * N * HW;
    __shared__ float tile[18][18];
    const int tid = threadIdx.x;
    const int tx = tid & 15, ty = tid >> 4;
    const int x0 = ((int)blockIdx.x % 12) * 16, y0 = ((int)blockIdx.x / 12) * 16;
    const int gx = x0 + tx, gy = y0 + ty;

    float acc[32];
    #pragma unroll
    for (int o = 0; o < 32; ++o) acc[o] = 0.f;

    for (int i = 0; i < 32; ++i) {
        __syncthreads();
        for (int idx = tid; idx < 18 * 18; idx += 256) {
            int xx = idx % 18, yy = idx / 18;
            int ggy = y0 + yy - 1, ggx = x0 + xx - 1;
            float v = 0.f;
            if (ggy >= 0 && ggy < Hh && ggx >= 0 && ggx < Ww)
                v = src[(size_t)i * HW + (size_t)ggy * Ww + ggx];
            tile[yy][xx] = v;
        }
        __syncthreads();
        float e[4];
        #pragma unroll
        for (int d = 0; d < 4; ++d) {
            size_t eidx = ((size_t)(b * 128) + i * 4 + d) * HW + (size_t)gy * Ww + gx;
            float num = ece_out[eidx], den = ce_out[eidx];
            e[d] = fminf(fmaxf(num / (den + EPSF), EPSF), 1.f);
        }
        float e9[9] = {e[0], e[1], e[2], e[3], 1.f, e[3], e[2], e[1], e[0]};
        float g[9];
        #pragma unroll
        for (int k = 0; k < 9; ++k) g[k] = tile[ty + k / 3][tx + k % 3] * e9[k];
        const float* wb = wd + (size_t)i * 9;
        #pragma unroll
        for (int o = 0; o < 32; ++o) {
            const float* wo = wb + (size_t)o * 32 * 9;   // block-uniform -> s_load
            float a = acc[o];
            #pragma unroll
            for (int k = 0; k < 9; ++k) a += wo[k] * g[k];
            acc[o] = a;
        }
    }
    #pragma unroll
    for (int o = 0; o < 32; ++o)
        out0[((size_t)((t * Bb + b) * N + o)) * HW + (size_t)gy * Ww + gx] = acc[o];
}

extern "C" void kernel_launch(void* const* d_in, const int* in_sizes, int n_in,
                              void* d_out, int out_size, void* d_ws, size_t ws_size,
                              hipStream_t stream)
{
    const float* x     = (const float*)d_in[0];
    const float* ece   = (const float*)d_in[1];
    const float* ce    = (const float*)d_in[2];
    const float* Wcd   = (const float*)d_in[3];
    const float* Wsd   = (const float*)d_in[4];
    const float* Wce   = (const float*)d_in[5];
    const float* Wse0  = (const float*)d_in[6];
    const float* Wse1  = (const float*)d_in[7];
    const float* Wse3  = (const float*)d_in[8];
    const float* Wdir  = (const float*)d_in[9];
    const float* Wpow  = (const float*)d_in[10];
    const float* Wprop = (const float*)d_in[11];
    float* out = (float*)d_out;
    float* ws  = (float*)d_ws;

    float* ce_in   = ws + OFF_CE_IN;
    float* ece_in  = ws + OFF_ECE_IN;
    float* out0    = out;
    float* ece_out = out + OUT0_SZ;
    float* ce_out  = out + OUT0_SZ + EOUT_SZ;

    prep_weights<<<1, 256, 0, stream>>>(Wcd, Wsd, Wce, Wse0, Wse1, Wse3, Wdir, Wpow, Wprop, ws);
    prep_inputs<<<dim3(Hh, N, Bb), 192, 0, stream>>>(x, ce, ece, ws, ce_in, ece_in);
    conv_e<<<dim3(144, 4, 4), 256, 0, stream>>>(ce_in, ece_in, ws + OFF_WCONV_E, ce_out, ece_out);
    conv_d<<<dim3(144, Bb, 2), 256, 0, stream>>>(x, ws + OFF_WCONV_D, ece_out, ce_out, out0);
}

// Round 2
// 537.788 us; speedup vs baseline: 2.9202x; 2.9202x over previous
//
#include <hip/hip_runtime.h>
#include <math.h>

#define EPSF 1e-20f
static constexpr int N  = 32;
static constexpr int Hh = 192;
static constexpr int Ww = 192;
static constexpr int Bb = 2;
static constexpr int HW = Hh * Ww;            // 36864

// workspace layout (bytes)
static constexpr size_t OFFB_WCONV_D = 0;          // 32*32*9 fp32      = 36864 B
static constexpr size_t OFFB_WPROP   = 36864;      // 32*4 fp32         = 512 B
static constexpr size_t OFFB_WPOW    = 37376;      // 32*8 fp32         = 1024 B
static constexpr size_t OFFB_WFRAG   = 40960;      // 9*16*128*8 bf16   = 294912 B
static constexpr size_t OFFB_CE_BF   = 335872;     // 2*HW*128 bf16     = 18874368 B
static constexpr size_t OFFB_ECE_BF  = OFFB_CE_BF + (size_t)2 * HW * 128 * 2;
// total ~36.3 MB (< previous 72.6 MB usage)

static constexpr size_t OUT0_SZ  = (size_t)4 * N * HW;      // 4,718,592
static constexpr size_t EOUT_SZ  = (size_t)Bb * N * 4 * HW; // 9,437,184

typedef short bf16x8 __attribute__((ext_vector_type(8)));
typedef float f32x4  __attribute__((ext_vector_type(4)));

__device__ __forceinline__ float softplusf(float x) { return log1pf(expf(x)); }
__device__ __forceinline__ float sigmf(float x)     { return 1.f / (1.f + expf(-x)); }
__device__ __forceinline__ unsigned short f2bf(float f) {
    unsigned int u = __float_as_uint(f);
    u = (u + 0x7fffu + ((u >> 16) & 1u)) >> 16;   // RNE
    return (unsigned short)u;
}

// ---------------------------------------------------------------- weights ---
__global__ void prep_weights(const float* __restrict__ Wcd, const float* __restrict__ Wsd,
                             const float* __restrict__ Wce, const float* __restrict__ Wse0,
                             const float* __restrict__ Wse1, const float* __restrict__ Wse3,
                             const float* __restrict__ Wdir, const float* __restrict__ Wpow,
                             const float* __restrict__ Wprop, char* __restrict__ wsb)
{
    __shared__ float s_wcd[32][32];
    __shared__ float s_wce[32][32];
    __shared__ float s_wsd[32][9];
    __shared__ float s_wse[32][4][9];
    __shared__ float s_wdir[4][32][4];
    const int tid = threadIdx.x;

    if (tid < 64) {
        int o = tid & 31;
        const float* src = (tid < 32) ? Wcd : Wce;
        float s = 0.f;
        for (int i = 0; i < 32; ++i) s += softplusf(src[o * 32 + i]);
        float inv = 1.f / s;
        for (int i = 0; i < 32; ++i) {
            float v = softplusf(src[o * 32 + i]) * inv;
            if (tid < 32) s_wcd[o][i] = v; else s_wce[o][i] = v;
        }
    }
    if (tid < 32) {
        int i = tid;
        float c0[3], c1[3]; float s = 0.f;
        for (int h = 0; h < 3; ++h) {
            c0[h] = softplusf(Wsd[(i * 3 + h) * 2 + 0]);
            c1[h] = softplusf(Wsd[(i * 3 + h) * 2 + 1]);
            s += 2.f * c0[h] + c1[h];
        }
        float inv = 1.f / s;
        for (int h = 0; h < 3; ++h) {
            s_wsd[i][h * 3 + 0] = c0[h] * inv;
            s_wsd[i][h * 3 + 1] = c1[h] * inv;
            s_wsd[i][h * 3 + 2] = c0[h] * inv;
        }
    }
    if (tid < 128) {
        int i = tid >> 2, d = tid & 3;
        float v[9];
        for (int h = 0; h < 3; ++h)
            for (int w = 0; w < 3; ++w) {
                float val;
                if (d == 0)      val = softplusf(Wse0[(i * 3 + h) * 3 + w]);
                else if (d == 1) val = softplusf(Wse1[(i * 3 + h) * 2 + (w == 1 ? 1 : 0)]);
                else if (d == 2) val = softplusf(Wse0[(i * 3 + h) * 3 + (2 - w)]);
                else             val = softplusf(Wse3[(i * 3 + h) * 2 + (w == 1 ? 1 : 0)]);
                v[h * 3 + w] = val;
            }
        float s = 0.f;
        for (int k = 0; k < 9; ++k) s += v[k];
        float inv = 1.f / s;
        for (int k = 0; k < 9; ++k) s_wse[i][d][k] = v[k] * inv;
    }
    if (tid < 128) {
        int p = tid >> 5, i = tid & 31;
        const int jmap[4][4] = {{0,1,2,3},{4,5,4,6},{2,1,0,3},{7,8,7,9}};
        float v[4]; float s = 0.f;
        for (int d = 0; d < 4; ++d) { v[d] = softplusf(Wdir[i * 10 + jmap[p][d]]); s += v[d]; }
        float inv = 1.f / s;
        for (int d = 0; d < 4; ++d) s_wdir[p][i][d] = v[d] * inv;
    }
    if (tid < 32) {
        int i = tid;
        float p0 = softplusf(Wpow[i*5+0]), p1 = softplusf(Wpow[i*5+1]), p2 = softplusf(Wpow[i*5+2]);
        float p3 = softplusf(Wpow[i*5+3]), p4 = softplusf(Wpow[i*5+4]);
        float* wp = (float*)(wsb + OFFB_WPOW) + (size_t)i * 8;
        wp[0]=p0; wp[1]=p2; wp[2]=p1; wp[3]=p4;   // s=0 (fwd)
        wp[4]=p1; wp[5]=p3; wp[6]=p0; wp[7]=p4;   // s=1 (bwd)
        float c0 = sigmf(Wprop[i*3+0]), c1 = sigmf(Wprop[i*3+1]), c2 = sigmf(Wprop[i*3+2]);
        float* pr = (float*)(wsb + OFFB_WPROP) + (size_t)i * 4;
        pr[0]=c1; pr[1]=c0; pr[2]=c1; pr[3]=c2;
    }
    __syncthreads();
    // w_conv_d[(o*32+i)*9+k] fp32
    float* wd = (float*)(wsb + OFFB_WCONV_D);
    for (int idx = tid; idx < 32 * 32 * 9; idx += 256) {
        int k = idx % 9; int t = idx / 9; int i = t & 31; int o = t >> 5;
        wd[idx] = s_wcd[o][i] * s_wsd[i][k];
    }
    // e-conv weights, bf16, A-fragment layout:
    // wfrag[((tap*16 + qq)*128 + oc)*8 + j], ic = qq*8 + j
    unsigned short* wfrag = (unsigned short*)(wsb + OFFB_WFRAG);
    for (int idx = tid; idx < 9 * 16 * 128 * 8; idx += 256) {
        int j  = idx & 7;
        int oc = (idx >> 3) & 127;
        int qq = (idx >> 10) & 15;
        int tap = idx >> 14;
        int ic = qq * 8 + j;
        int o = oc >> 2, p = oc & 3, i = ic >> 2, d = ic & 3;
        float v = s_wce[o][i] * s_wdir[p][i][d] * s_wse[i][d][tap];
        wfrag[idx] = f2bf(v);
    }
}

// -------------------------------------------------------------- ce/ece in ---
// outputs channel-last bf16: arr[((b*HW + pix)*128) + i*4 + d]
__global__ __launch_bounds__(192) void prep_inputs(
    const float* __restrict__ xin, const float* __restrict__ ce,
    const float* __restrict__ ece, const char* __restrict__ wsb,
    unsigned short* __restrict__ ce_bf, unsigned short* __restrict__ ece_bf)
{
    const int x = threadIdx.x;      // 0..191
    const int y = blockIdx.x;       // 0..191
    const int i = blockIdx.y;       // 0..31
    const int b = blockIdx.z;       // 0..1
    const float* dcd = xin + ((size_t)(b * N + i)) * HW;
    const float* cd  = xin + ((size_t)((Bb + b) * N + i)) * HW;

    float cdv[3][3], dv[3][3];
    #pragma unroll
    for (int dy = -1; dy <= 1; ++dy)
        #pragma unroll
        for (int dx = -1; dx <= 1; ++dx) {
            int yy = y + dy, xx = x + dx;
            bool in = (yy >= 0 && yy < Hh && xx >= 0 && xx < Ww);
            float c = in ? cd[yy * Ww + xx] : 0.f;
            float dd = in ? dcd[yy * Ww + xx] : 0.f;
            cdv[dy + 1][dx + 1] = c;
            dv[dy + 1][dx + 1] = in ? dd / (c + EPSF) : 0.f;
        }
    const float* wprop = (const float*)(wsb + OFFB_WPROP);
    const float* wpow  = (const float*)(wsb + OFFB_WPOW);
    const int oy[4] = {-1, -1, -1, 0}, ox[4] = {-1, 0, 1, 1};
    unsigned short cev[4], ecev[4];
    #pragma unroll
    for (int d = 0; d < 4; ++d) {
        float nf = dv[1 + oy[d]][1 + ox[d]];
        float df = dv[1 - oy[d]][1 - ox[d]];
        float rf = nf / (df + EPSF);
        float rb = df / (nf + EPSF);
        float p0 = wpow[i * 8 + d], p1 = wpow[i * 8 + 4 + d];
        float ef = powf(fminf(fmaxf(rf, EPSF), 1.f), p0);
        float eb = powf(fminf(fmaxf(rb, EPSF), 1.f), p1);
        float en = fminf(fmaxf(fminf(ef, eb), 0.f), 1.f);
        float cn = cdv[1 + oy[d]][1 + ox[d]] * cdv[1 - oy[d]][1 - ox[d]];
        float wp = wprop[i * 4 + d];
        size_t idx = ((size_t)(b * 128 + i * 4 + d)) * HW + (size_t)y * Ww + x;
        cev[d]  = f2bf(ce[idx] * wp + cn * (1.f - wp));
        ecev[d] = f2bf(ece[idx] * wp + en * cn * (1.f - wp));
    }
    size_t off = ((size_t)b * HW + (size_t)y * Ww + x) * 128 + i * 4;
    *(ushort4*)(ce_bf + off)  = make_ushort4(cev[0], cev[1], cev[2], cev[3]);
    *(ushort4*)(ece_bf + off) = make_ushort4(ecev[0], ecev[1], ecev[2], ecev[3]);
}

// ------------------------------------------- 128->128 3x3 conv via MFMA -----
// block: 128 oc x 64 px (16 wide x 4 tall); 4 waves, wave w -> oc [w*32, w*32+32)
__global__ __launch_bounds__(256) void conv_e_mfma(
    const unsigned short* __restrict__ ce_bf, const unsigned short* __restrict__ ece_bf,
    const unsigned short* __restrict__ wfrag,
    float* __restrict__ ce_out, float* __restrict__ ece_out)
{
    const int z = blockIdx.z; const int t = z >> 1; const int b = z & 1;
    const unsigned short* in_bf = (t ? ece_bf : ce_bf) + (size_t)b * HW * 128;
    float* outp = t ? ece_out : ce_out;

    // halo tile: 6 rows x 18 cols x 128 ch, per-pixel stride padded to 136 bf16
    __shared__ unsigned short tile[108 * 136];   // 29376 B

    const int tid  = threadIdx.x;
    const int lane = tid & 63;
    const int l16  = lane & 15;
    const int quad = lane >> 4;          // 0..3
    const int wave = tid >> 6;           // 0..3
    const int woc  = wave * 32;
    const int x0 = ((int)blockIdx.x % 12) * 16;
    const int y0 = ((int)blockIdx.x / 12) * 4;

    // ---- stage 108 pixels x 128 ch (bf16) : 1728 x 16B chunks ----
    {
        const uint4* gsrc = (const uint4*)in_bf;    // 16B = 8 ch
        for (int idx = tid; idx < 108 * 16; idx += 256) {
            int p = idx >> 4, c = idx & 15;
            int hy = p / 18, hx = p - hy * 18;
            int gy = y0 + hy - 1, gx = x0 + hx - 1;
            uint4 v = make_uint4(0u, 0u, 0u, 0u);
            if (gy >= 0 && gy < Hh && gx >= 0 && gx < Ww)
                v = gsrc[(size_t)(gy * Ww + gx) * 16 + c];
            *(uint4*)&tile[p * 136 + c * 8] = v;
        }
    }
    __syncthreads();

    f32x4 acc[2][4];
    #pragma unroll
    for (int mt = 0; mt < 2; ++mt)
        #pragma unroll
        for (int nt = 0; nt < 4; ++nt) acc[mt][nt] = (f32x4){0.f, 0.f, 0.f, 0.f};

    #pragma unroll
    for (int tap = 0; tap < 9; ++tap) {
        const int ky = tap / 3, kx = tap % 3;
        #pragma unroll
        for (int q = 0; q < 4; ++q) {
            const unsigned short* wb = wfrag + (size_t)((tap * 16 + q * 4 + quad) * 128) * 8;
            bf16x8 a0 = *(const bf16x8*)(wb + (woc + l16) * 8);
            bf16x8 a1 = *(const bf16x8*)(wb + (woc + 16 + l16) * 8);
            #pragma unroll
            for (int nt = 0; nt < 4; ++nt) {
                int p = (nt + ky) * 18 + (l16 + kx);
                bf16x8 bv = *(const bf16x8*)&tile[p * 136 + q * 32 + quad * 8];
                acc[0][nt] = __builtin_amdgcn_mfma_f32_16x16x32_bf16(a0, bv, acc[0][nt], 0, 0, 0);
                acc[1][nt] = __builtin_amdgcn_mfma_f32_16x16x32_bf16(a1, bv, acc[1][nt], 0, 0, 0);
            }
        }
    }

    // C/D layout: col(n)=lane&15, row(m)=quad*4+reg
    #pragma unroll
    for (int mt = 0; mt < 2; ++mt)
        #pragma unroll
        for (int nt = 0; nt < 4; ++nt) {
            int y = y0 + nt, x = x0 + l16;
            #pragma unroll
            for (int r = 0; r < 4; ++r) {
                int oc = woc + mt * 16 + quad * 4 + r;
                outp[((size_t)b * 128 + oc) * HW + (size_t)y * Ww + x] = acc[mt][nt][r];
            }
        }
}

// --------------------------------------- gated 32->32 conv (dcd_out/cd_out) --
__global__ __launch_bounds__(256) void conv_d(
    const float* __restrict__ xin, const float* __restrict__ wd,
    const float* __restrict__ ece_out, const float* __restrict__ ce_out,
    float* __restrict__ out0)
{
    const int b = blockIdx.y;   // 0..1
    const int t = blockIdx.z;   // 0: dcd, 1: cd
    const float* src = xin + ((size_t)(t * Bb + b)) * N * HW;
    __shared__ float tile[18][18];
    const int tid = threadIdx.x;
    const int tx = tid & 15, ty = tid >> 4;
    const int x0 = ((int)blockIdx.x % 12) * 16, y0 = ((int)blockIdx.x / 12) * 16;
    const int gx = x0 + tx, gy = y0 + ty;

    float acc[32];
    #pragma unroll
    for (int o = 0; o < 32; ++o) acc[o] = 0.f;

    for (int i = 0; i < 32; ++i) {
        __syncthreads();
        for (int idx = tid; idx < 18 * 18; idx += 256) {
            int xx = idx % 18, yy = idx / 18;
            int ggy = y0 + yy - 1, ggx = x0 + xx - 1;
            float v = 0.f;
            if (ggy >= 0 && ggy < Hh && ggx >= 0 && ggx < Ww)
                v = src[(size_t)i * HW + (size_t)ggy * Ww + ggx];
            tile[yy][xx] = v;
        }
        __syncthreads();
        float e[4];
        #pragma unroll
        for (int d = 0; d < 4; ++d) {
            size_t eidx = ((size_t)(b * 128) + i * 4 + d) * HW + (size_t)gy * Ww + gx;
            float num = ece_out[eidx], den = ce_out[eidx];
            e[d] = fminf(fmaxf(num / (den + EPSF), EPSF), 1.f);
        }
        float e9[9] = {e[0], e[1], e[2], e[3], 1.f, e[3], e[2], e[1], e[0]};
        float g[9];
        #pragma unroll
        for (int k = 0; k < 9; ++k) g[k] = tile[ty + k / 3][tx + k % 3] * e9[k];
        const float* wb = wd + (size_t)i * 9;
        #pragma unroll
        for (int o = 0; o < 32; ++o) {
            const float* wo = wb + (size_t)o * 32 * 9;   // block-uniform -> s_load
            float a = acc[o];
            #pragma unroll
            for (int k = 0; k < 9; ++k) a += wo[k] * g[k];
            acc[o] = a;
        }
    }
    #pragma unroll
    for (int o = 0; o < 32; ++o)
        out0[((size_t)((t * Bb + b) * N + o)) * HW + (size_t)gy * Ww + gx] = acc[o];
}

extern "C" void kernel_launch(void* const* d_in, const int* in_sizes, int n_in,
                              void* d_out, int out_size, void* d_ws, size_t ws_size,
                              hipStream_t stream)
{
    const float* x     = (const float*)d_in[0];
    const float* ece   = (const float*)d_in[1];
    const float* ce    = (const float*)d_in[2];
    const float* Wcd   = (const float*)d_in[3];
    const float* Wsd   = (const float*)d_in[4];
    const float* Wce   = (const float*)d_in[5];
    const float* Wse0  = (const float*)d_in[6];
    const float* Wse1  = (const float*)d_in[7];
    const float* Wse3  = (const float*)d_in[8];
    const float* Wdir  = (const float*)d_in[9];
    const float* Wpow  = (const float*)d_in[10];
    const float* Wprop = (const float*)d_in[11];
    float* out = (float*)d_out;
    char* wsb  = (char*)d_ws;

    unsigned short* ce_bf  = (unsigned short*)(wsb + OFFB_CE_BF);
    unsigned short* ece_bf = (unsigned short*)(wsb + OFFB_ECE_BF);
    unsigned short* wfrag  = (unsigned short*)(wsb + OFFB_WFRAG);
    float* out0    = out;
    float* ece_out = out + OUT0_SZ;
    float* ce_out  = out + OUT0_SZ + EOUT_SZ;

    prep_weights<<<1, 256, 0, stream>>>(Wcd, Wsd, Wce, Wse0, Wse1, Wse3, Wdir, Wpow, Wprop, wsb);
    prep_inputs<<<dim3(Hh, N, Bb), 192, 0, stream>>>(x, ce, ece, wsb, ce_bf, ece_bf);
    conv_e_mfma<<<dim3(576, 1, 4), 256, 0, stream>>>(ce_bf, ece_bf, wfrag, ce_out, ece_out);
    conv_d<<<dim3(144, Bb, 2), 256, 0, stream>>>(x, (const float*)(wsb + OFFB_WCONV_D), ece_out, ce_out, out0);
}

// Round 3
// 414.914 us; speedup vs baseline: 3.7850x; 1.2961x over previous
//
#include <hip/hip_runtime.h>
#include <math.h>

#define EPSF 1e-20f
static constexpr int N  = 32;
static constexpr int Hh = 192;
static constexpr int Ww = 192;
static constexpr int Bb = 2;
static constexpr int HW = Hh * Ww;            // 36864

// workspace layout (bytes)
static constexpr size_t OFFB_WDFRAG  = 0;          // 9*4*32*8 bf16     = 18432 B
static constexpr size_t OFFB_WPROP   = 36864;      // 32*4 fp32         = 512 B
static constexpr size_t OFFB_WPOW    = 37376;      // 32*8 fp32         = 1024 B
static constexpr size_t OFFB_WFRAG   = 40960;      // 9*16*128*8 bf16   = 294912 B
static constexpr size_t OFFB_CE_BF   = 335872;     // 2*HW*128 bf16     = 18874368 B
static constexpr size_t OFFB_ECE_BF  = OFFB_CE_BF + (size_t)2 * HW * 128 * 2;

static constexpr size_t OUT0_SZ  = (size_t)4 * N * HW;      // 4,718,592
static constexpr size_t EOUT_SZ  = (size_t)Bb * N * 4 * HW; // 9,437,184

typedef short bf16x8 __attribute__((ext_vector_type(8)));
typedef float f32x4  __attribute__((ext_vector_type(4)));

__device__ __forceinline__ float softplusf(float x) { return log1pf(expf(x)); }
__device__ __forceinline__ float sigmf(float x)     { return 1.f / (1.f + expf(-x)); }
__device__ __forceinline__ unsigned short f2bf(float f) {
    unsigned int u = __float_as_uint(f);
    u = (u + 0x7fffu + ((u >> 16) & 1u)) >> 16;   // RNE
    return (unsigned short)u;
}
// packed bf16 elementwise multiply (round-half-up repack; inputs in [0,1])
__device__ __forceinline__ bf16x8 bfmul8(bf16x8 a, bf16x8 b) {
    union U { bf16x8 v; unsigned int u[4]; };
    U ua, ub, r; ua.v = a; ub.v = b;
    #pragma unroll
    for (int i = 0; i < 4; ++i) {
        float alo = __uint_as_float(ua.u[i] << 16);
        float ahi = __uint_as_float(ua.u[i] & 0xffff0000u);
        float blo = __uint_as_float(ub.u[i] << 16);
        float bhi = __uint_as_float(ub.u[i] & 0xffff0000u);
        unsigned int lo = __float_as_uint(alo * blo);
        unsigned int hi = __float_as_uint(ahi * bhi);
        lo = (lo + 0x8000u) >> 16;
        hi = (hi + 0x8000u) & 0xffff0000u;
        r.u[i] = hi | lo;
    }
    return r.v;
}

// ---------------------------------------------------------------- weights ---
__global__ void prep_weights(const float* __restrict__ Wcd, const float* __restrict__ Wsd,
                             const float* __restrict__ Wce, const float* __restrict__ Wse0,
                             const float* __restrict__ Wse1, const float* __restrict__ Wse3,
                             const float* __restrict__ Wdir, const float* __restrict__ Wpow,
                             const float* __restrict__ Wprop, char* __restrict__ wsb)
{
    __shared__ float s_wcd[32][32];
    __shared__ float s_wce[32][32];
    __shared__ float s_wsd[32][9];
    __shared__ float s_wse[32][4][9];
    __shared__ float s_wdir[4][32][4];
    const int tid = threadIdx.x;

    if (tid < 64) {
        int o = tid & 31;
        const float* src = (tid < 32) ? Wcd : Wce;
        float s = 0.f;
        for (int i = 0; i < 32; ++i) s += softplusf(src[o * 32 + i]);
        float inv = 1.f / s;
        for (int i = 0; i < 32; ++i) {
            float v = softplusf(src[o * 32 + i]) * inv;
            if (tid < 32) s_wcd[o][i] = v; else s_wce[o][i] = v;
        }
    }
    if (tid < 32) {
        int i = tid;
        float c0[3], c1[3]; float s = 0.f;
        for (int h = 0; h < 3; ++h) {
            c0[h] = softplusf(Wsd[(i * 3 + h) * 2 + 0]);
            c1[h] = softplusf(Wsd[(i * 3 + h) * 2 + 1]);
            s += 2.f * c0[h] + c1[h];
        }
        float inv = 1.f / s;
        for (int h = 0; h < 3; ++h) {
            s_wsd[i][h * 3 + 0] = c0[h] * inv;
            s_wsd[i][h * 3 + 1] = c1[h] * inv;
            s_wsd[i][h * 3 + 2] = c0[h] * inv;
        }
    }
    if (tid < 128) {
        int i = tid >> 2, d = tid & 3;
        float v[9];
        for (int h = 0; h < 3; ++h)
            for (int w = 0; w < 3; ++w) {
                float val;
                if (d == 0)      val = softplusf(Wse0[(i * 3 + h) * 3 + w]);
                else if (d == 1) val = softplusf(Wse1[(i * 3 + h) * 2 + (w == 1 ? 1 : 0)]);
                else if (d == 2) val = softplusf(Wse0[(i * 3 + h) * 3 + (2 - w)]);
                else             val = softplusf(Wse3[(i * 3 + h) * 2 + (w == 1 ? 1 : 0)]);
                v[h * 3 + w] = val;
            }
        float s = 0.f;
        for (int k = 0; k < 9; ++k) s += v[k];
        float inv = 1.f / s;
        for (int k = 0; k < 9; ++k) s_wse[i][d][k] = v[k] * inv;
    }
    if (tid < 128) {
        int p = tid >> 5, i = tid & 31;
        const int jmap[4][4] = {{0,1,2,3},{4,5,4,6},{2,1,0,3},{7,8,7,9}};
        float v[4]; float s = 0.f;
        for (int d = 0; d < 4; ++d) { v[d] = softplusf(Wdir[i * 10 + jmap[p][d]]); s += v[d]; }
        float inv = 1.f / s;
        for (int d = 0; d < 4; ++d) s_wdir[p][i][d] = v[d] * inv;
    }
    if (tid < 32) {
        int i = tid;
        float p0 = softplusf(Wpow[i*5+0]), p1 = softplusf(Wpow[i*5+1]), p2 = softplusf(Wpow[i*5+2]);
        float p3 = softplusf(Wpow[i*5+3]), p4 = softplusf(Wpow[i*5+4]);
        float* wp = (float*)(wsb + OFFB_WPOW) + (size_t)i * 8;
        wp[0]=p0; wp[1]=p2; wp[2]=p1; wp[3]=p4;   // s=0 (fwd)
        wp[4]=p1; wp[5]=p3; wp[6]=p0; wp[7]=p4;   // s=1 (bwd)
        float c0 = sigmf(Wprop[i*3+0]), c1 = sigmf(Wprop[i*3+1]), c2 = sigmf(Wprop[i*3+2]);
        float* pr = (float*)(wsb + OFFB_WPROP) + (size_t)i * 4;
        pr[0]=c1; pr[1]=c0; pr[2]=c1; pr[3]=c2;
    }
    __syncthreads();
    // conv_d weights in A-fragment bf16 layout: wdf[((tap*4+quad)*32+oc)*8+j], ic=quad*8+j
    unsigned short* wdf = (unsigned short*)(wsb + OFFB_WDFRAG);
    for (int idx = tid; idx < 9 * 4 * 32 * 8; idx += 256) {
        int j = idx & 7, oc = (idx >> 3) & 31, quad = (idx >> 8) & 3, tap = idx >> 10;
        int i = quad * 8 + j;
        wdf[idx] = f2bf(s_wcd[oc][i] * s_wsd[i][tap]);
    }
    // e-conv weights, bf16, A-fragment layout:
    unsigned short* wfrag = (unsigned short*)(wsb + OFFB_WFRAG);
    for (int idx = tid; idx < 9 * 16 * 128 * 8; idx += 256) {
        int j  = idx & 7;
        int oc = (idx >> 3) & 127;
        int qq = (idx >> 10) & 15;
        int tap = idx >> 14;
        int ic = qq * 8 + j;
        int o = oc >> 2, p = oc & 3, i = ic >> 2, d = ic & 3;
        float v = s_wce[o][i] * s_wdir[p][i][d] * s_wse[i][d][tap];
        wfrag[idx] = f2bf(v);
    }
}

// -------------------------------------------------------------- ce/ece in ---
__global__ __launch_bounds__(192) void prep_inputs(
    const float* __restrict__ xin, const float* __restrict__ ce,
    const float* __restrict__ ece, const char* __restrict__ wsb,
    unsigned short* __restrict__ ce_bf, unsigned short* __restrict__ ece_bf)
{
    const int x = threadIdx.x;      // 0..191
    const int y = blockIdx.x;       // 0..191
    const int i = blockIdx.y;       // 0..31
    const int b = blockIdx.z;       // 0..1
    const float* dcd = xin + ((size_t)(b * N + i)) * HW;
    const float* cd  = xin + ((size_t)((Bb + b) * N + i)) * HW;

    float cdv[3][3], dv[3][3];
    #pragma unroll
    for (int dy = -1; dy <= 1; ++dy)
        #pragma unroll
        for (int dx = -1; dx <= 1; ++dx) {
            int yy = y + dy, xx = x + dx;
            bool in = (yy >= 0 && yy < Hh && xx >= 0 && xx < Ww);
            float c = in ? cd[yy * Ww + xx] : 0.f;
            float dd = in ? dcd[yy * Ww + xx] : 0.f;
            cdv[dy + 1][dx + 1] = c;
            dv[dy + 1][dx + 1] = in ? dd / (c + EPSF) : 0.f;
        }
    const float* wprop = (const float*)(wsb + OFFB_WPROP);
    const float* wpow  = (const float*)(wsb + OFFB_WPOW);
    const int oy[4] = {-1, -1, -1, 0}, ox[4] = {-1, 0, 1, 1};
    unsigned short cev[4], ecev[4];
    #pragma unroll
    for (int d = 0; d < 4; ++d) {
        float nf = dv[1 + oy[d]][1 + ox[d]];
        float df = dv[1 - oy[d]][1 - ox[d]];
        float rf = nf / (df + EPSF);
        float rb = df / (nf + EPSF);
        float p0 = wpow[i * 8 + d], p1 = wpow[i * 8 + 4 + d];
        float ef = powf(fminf(fmaxf(rf, EPSF), 1.f), p0);
        float eb = powf(fminf(fmaxf(rb, EPSF), 1.f), p1);
        float en = fminf(fmaxf(fminf(ef, eb), 0.f), 1.f);
        float cn = cdv[1 + oy[d]][1 + ox[d]] * cdv[1 - oy[d]][1 - ox[d]];
        float wp = wprop[i * 4 + d];
        size_t idx = ((size_t)(b * 128 + i * 4 + d)) * HW + (size_t)y * Ww + x;
        cev[d]  = f2bf(ce[idx] * wp + cn * (1.f - wp));
        ecev[d] = f2bf(ece[idx] * wp + en * cn * (1.f - wp));
    }
    size_t off = ((size_t)b * HW + (size_t)y * Ww + x) * 128 + i * 4;
    *(ushort4*)(ce_bf + off)  = make_ushort4(cev[0], cev[1], cev[2], cev[3]);
    *(ushort4*)(ece_bf + off) = make_ushort4(ecev[0], ecev[1], ecev[2], ecev[3]);
}

// ------------------------------------------- 128->128 3x3 conv via MFMA -----
__global__ __launch_bounds__(256) void conv_e_mfma(
    const unsigned short* __restrict__ ce_bf, const unsigned short* __restrict__ ece_bf,
    const unsigned short* __restrict__ wfrag,
    float* __restrict__ ce_out, float* __restrict__ ece_out)
{
    const int z = blockIdx.z; const int t = z >> 1; const int b = z & 1;
    const unsigned short* in_bf = (t ? ece_bf : ce_bf) + (size_t)b * HW * 128;
    float* outp = t ? ece_out : ce_out;

    __shared__ unsigned short tile[108 * 136];   // 29376 B

    const int tid  = threadIdx.x;
    const int lane = tid & 63;
    const int l16  = lane & 15;
    const int quad = lane >> 4;
    const int wave = tid >> 6;
    const int woc  = wave * 32;
    const int x0 = ((int)blockIdx.x % 12) * 16;
    const int y0 = ((int)blockIdx.x / 12) * 4;

    {
        const uint4* gsrc = (const uint4*)in_bf;
        for (int idx = tid; idx < 108 * 16; idx += 256) {
            int p = idx >> 4, c = idx & 15;
            int hy = p / 18, hx = p - hy * 18;
            int gy = y0 + hy - 1, gx = x0 + hx - 1;
            uint4 v = make_uint4(0u, 0u, 0u, 0u);
            if (gy >= 0 && gy < Hh && gx >= 0 && gx < Ww)
                v = gsrc[(size_t)(gy * Ww + gx) * 16 + c];
            *(uint4*)&tile[p * 136 + c * 8] = v;
        }
    }
    __syncthreads();

    f32x4 acc[2][4];
    #pragma unroll
    for (int mt = 0; mt < 2; ++mt)
        #pragma unroll
        for (int nt = 0; nt < 4; ++nt) acc[mt][nt] = (f32x4){0.f, 0.f, 0.f, 0.f};

    #pragma unroll
    for (int tap = 0; tap < 9; ++tap) {
        const int ky = tap / 3, kx = tap % 3;
        #pragma unroll
        for (int q = 0; q < 4; ++q) {
            const unsigned short* wb = wfrag + (size_t)((tap * 16 + q * 4 + quad) * 128) * 8;
            bf16x8 a0 = *(const bf16x8*)(wb + (woc + l16) * 8);
            bf16x8 a1 = *(const bf16x8*)(wb + (woc + 16 + l16) * 8);
            #pragma unroll
            for (int nt = 0; nt < 4; ++nt) {
                int p = (nt + ky) * 18 + (l16 + kx);
                bf16x8 bv = *(const bf16x8*)&tile[p * 136 + q * 32 + quad * 8];
                acc[0][nt] = __builtin_amdgcn_mfma_f32_16x16x32_bf16(a0, bv, acc[0][nt], 0, 0, 0);
                acc[1][nt] = __builtin_amdgcn_mfma_f32_16x16x32_bf16(a1, bv, acc[1][nt], 0, 0, 0);
            }
        }
    }

    #pragma unroll
    for (int mt = 0; mt < 2; ++mt)
        #pragma unroll
        for (int nt = 0; nt < 4; ++nt) {
            int y = y0 + nt, x = x0 + l16;
            #pragma unroll
            for (int r = 0; r < 4; ++r) {
                int oc = woc + mt * 16 + quad * 4 + r;
                outp[((size_t)b * 128 + oc) * HW + (size_t)y * Ww + x] = acc[mt][nt][r];
            }
        }
}

// ----------------------- gated 32->32 conv via MFMA (dcd_out & cd_out) ------
// block: 16x4 pixel tile, fixed b. 4 waves: wave = t*2 + nhalf.
// LDS: xt[t][halo 108 px][32ch] bf16 (stride 40), Ebf[d][64 px][32ch] (stride 40)
__global__ __launch_bounds__(256) void conv_d_mfma(
    const float* __restrict__ xin, const unsigned short* __restrict__ wdfrag,
    const float* __restrict__ ece_out, const float* __restrict__ ce_out,
    float* __restrict__ out0)
{
    const int b = blockIdx.y;
    __shared__ unsigned short xt[2][108 * 40];   // 17280 B
    __shared__ unsigned short Ebf[4 * 64 * 40];  // 20480 B

    const int tid  = threadIdx.x;
    const int lane = tid & 63;
    const int l16  = lane & 15;
    const int quad = lane >> 4;
    const int wave = tid >> 6;
    const int t    = wave >> 1;      // 0: dcd, 1: cd
    const int nh   = wave & 1;       // pixel half
    const int x0 = ((int)blockIdx.x % 12) * 16;
    const int y0 = ((int)blockIdx.x / 12) * 4;

    // stage dcd & cd halo tiles as channel-last bf16
    for (int idx = tid; idx < 2 * 32 * 108; idx += 256) {
        int hp = idx % 108;
        int r = idx / 108; int i = r & 31; int tt = r >> 5;
        int hy = hp / 18, hx = hp - hy * 18;
        int gy = y0 + hy - 1, gx = x0 + hx - 1;
        float v = 0.f;
        if (gy >= 0 && gy < Hh && gx >= 0 && gx < Ww)
            v = xin[((size_t)((tt * Bb + b) * N + i)) * HW + (size_t)gy * Ww + gx];
        xt[tt][hp * 40 + i] = f2bf(v);
    }
    // stage e-gate: e = clip(ece_out/(ce_out+eps), eps, 1)
    for (int idx = tid; idx < 32 * 64; idx += 256) {
        int px = idx & 15, py = (idx >> 4) & 3, i = idx >> 6;
        size_t gp = (size_t)(y0 + py) * Ww + x0 + px;
        int p = py * 16 + px;
        #pragma unroll
        for (int d = 0; d < 4; ++d) {
            size_t eidx = ((size_t)(b * 128 + i * 4 + d)) * HW + gp;
            float e = fminf(fmaxf(ece_out[eidx] / (ce_out[eidx] + EPSF), EPSF), 1.f);
            Ebf[(d * 64 + p) * 40 + i] = f2bf(e);
        }
    }
    __syncthreads();

    f32x4 acc[2][2];   // [ntile][mtile]
    #pragma unroll
    for (int nt = 0; nt < 2; ++nt)
        #pragma unroll
        for (int mt = 0; mt < 2; ++mt) acc[nt][mt] = (f32x4){0.f, 0.f, 0.f, 0.f};

    const int dmap[9] = {0, 1, 2, 3, 0, 3, 2, 1, 0};   // index 4 unused
    #pragma unroll
    for (int tap = 0; tap < 9; ++tap) {
        const int ky = tap / 3, kx = tap % 3;
        bf16x8 a0 = *(const bf16x8*)(wdfrag + (size_t)(((tap * 4 + quad) * 32) + l16) * 8);
        bf16x8 a1 = *(const bf16x8*)(wdfrag + (size_t)(((tap * 4 + quad) * 32) + 16 + l16) * 8);
        #pragma unroll
        for (int nt = 0; nt < 2; ++nt) {
            int p = nh * 32 + nt * 16 + l16;
            int py = p >> 4, px = p & 15;
            int hp = (py + ky) * 18 + px + kx;
            bf16x8 xv = *(const bf16x8*)&xt[t][hp * 40 + quad * 8];
            bf16x8 g;
            if (tap == 4) g = xv;
            else {
                bf16x8 ev = *(const bf16x8*)&Ebf[(dmap[tap] * 64 + p) * 40 + quad * 8];
                g = bfmul8(xv, ev);
            }
            acc[nt][0] = __builtin_amdgcn_mfma_f32_16x16x32_bf16(a0, g, acc[nt][0], 0, 0, 0);
            acc[nt][1] = __builtin_amdgcn_mfma_f32_16x16x32_bf16(a1, g, acc[nt][1], 0, 0, 0);
        }
    }

    // C/D: col(n)=l16 -> pixel, row(m)=quad*4+r -> oc
    #pragma unroll
    for (int nt = 0; nt < 2; ++nt) {
        int p = nh * 32 + nt * 16 + l16;
        int py = p >> 4, px = p & 15;
        size_t gp = (size_t)(y0 + py) * Ww + x0 + px;
        #pragma unroll
        for (int mt = 0; mt < 2; ++mt)
            #pragma unroll
            for (int r = 0; r < 4; ++r) {
                int oc = mt * 16 + quad * 4 + r;
                out0[((size_t)((t * Bb + b) * N + oc)) * HW + gp] = acc[nt][mt][r];
            }
    }
}

extern "C" void kernel_launch(void* const* d_in, const int* in_sizes, int n_in,
                              void* d_out, int out_size, void* d_ws, size_t ws_size,
                              hipStream_t stream)
{
    const float* x     = (const float*)d_in[0];
    const float* ece   = (const float*)d_in[1];
    const float* ce    = (const float*)d_in[2];
    const float* Wcd   = (const float*)d_in[3];
    const float* Wsd   = (const float*)d_in[4];
    const float* Wce   = (const float*)d_in[5];
    const float* Wse0  = (const float*)d_in[6];
    const float* Wse1  = (const float*)d_in[7];
    const float* Wse3  = (const float*)d_in[8];
    const float* Wdir  = (const float*)d_in[9];
    const float* Wpow  = (const float*)d_in[10];
    const float* Wprop = (const float*)d_in[11];
    float* out = (float*)d_out;
    char* wsb  = (char*)d_ws;

    unsigned short* ce_bf  = (unsigned short*)(wsb + OFFB_CE_BF);
    unsigned short* ece_bf = (unsigned short*)(wsb + OFFB_ECE_BF);
    unsigned short* wfrag  = (unsigned short*)(wsb + OFFB_WFRAG);
    unsigned short* wdfrag = (unsigned short*)(wsb + OFFB_WDFRAG);
    float* out0    = out;
    float* ece_out = out + OUT0_SZ;
    float* ce_out  = out + OUT0_SZ + EOUT_SZ;

    prep_weights<<<1, 256, 0, stream>>>(Wcd, Wsd, Wce, Wse0, Wse1, Wse3, Wdir, Wpow, Wprop, wsb);
    prep_inputs<<<dim3(Hh, N, Bb), 192, 0, stream>>>(x, ce, ece, wsb, ce_bf, ece_bf);
    conv_e_mfma<<<dim3(576, 1, 4), 256, 0, stream>>>(ce_bf, ece_bf, wfrag, ce_out, ece_out);
    conv_d_mfma<<<dim3(576, Bb), 256, 0, stream>>>(x, wdfrag, ece_out, ce_out, out0);
}

// Round 5
// 380.075 us; speedup vs baseline: 4.1320x; 1.0917x over previous
//
#include <hip/hip_runtime.h>
#include <math.h>

#define EPSF 1e-20f
static constexpr int N  = 32;
static constexpr int Hh = 192;
static constexpr int Ww = 192;
static constexpr int Bb = 2;
static constexpr int HW = Hh * Ww;            // 36864

// workspace layout (bytes)
static constexpr size_t OFFB_WDFRAG  = 0;          // 9*4*32*8 bf16     = 18432 B
static constexpr size_t OFFB_WPROP   = 36864;      // 32*4 fp32         = 512 B
static constexpr size_t OFFB_WPOW    = 37376;      // 32*8 fp32         = 1024 B
static constexpr size_t OFFB_WFRAG   = 40960;      // 9*16*128*8 bf16   = 294912 B
static constexpr size_t OFFB_CE_BF   = 335872;     // 2*HW*128 bf16     = 18874368 B
static constexpr size_t OFFB_ECE_BF  = OFFB_CE_BF + (size_t)2 * HW * 128 * 2;

static constexpr size_t OUT0_SZ  = (size_t)4 * N * HW;      // 4,718,592
static constexpr size_t EOUT_SZ  = (size_t)Bb * N * 4 * HW; // 9,437,184

typedef short bf16x8 __attribute__((ext_vector_type(8)));
typedef float f32x4  __attribute__((ext_vector_type(4)));

__device__ __forceinline__ float softplusf(float x) { return log1pf(expf(x)); }
__device__ __forceinline__ float sigmf(float x)     { return 1.f / (1.f + expf(-x)); }
__device__ __forceinline__ unsigned short f2bf(float f) {
    unsigned int u = __float_as_uint(f);
    u = (u + 0x7fffu + ((u >> 16) & 1u)) >> 16;   // RNE
    return (unsigned short)u;
}
// fast reciprocal: v_rcp_f32 (~1 ulp; output feeds bf16 so plenty)
__device__ __forceinline__ float frcp(float x) { return __builtin_amdgcn_rcpf(x); }
// fast pow for base in [1e-20, 1], p >= 0: v_log_f32 + v_exp_f32
__device__ __forceinline__ float fpow01(float r, float p) {
    return __builtin_amdgcn_exp2f(p * __builtin_amdgcn_logf(r));
}
// packed bf16 elementwise multiply (round-half-up repack; inputs in [0,1])
__device__ __forceinline__ bf16x8 bfmul8(bf16x8 a, bf16x8 b) {
    union U { bf16x8 v; unsigned int u[4]; };
    U ua, ub, r; ua.v = a; ub.v = b;
    #pragma unroll
    for (int i = 0; i < 4; ++i) {
        float alo = __uint_as_float(ua.u[i] << 16);
        float ahi = __uint_as_float(ua.u[i] & 0xffff0000u);
        float blo = __uint_as_float(ub.u[i] << 16);
        float bhi = __uint_as_float(ub.u[i] & 0xffff0000u);
        unsigned int lo = __float_as_uint(alo * blo);
        unsigned int hi = __float_as_uint(ahi * bhi);
        lo = (lo + 0x8000u) >> 16;
        hi = (hi + 0x8000u) & 0xffff0000u;
        r.u[i] = hi | lo;
    }
    return r.v;
}

// ---------------------------------------------------------------- weights ---
__global__ void prep_weights(const float* __restrict__ Wcd, const float* __restrict__ Wsd,
                             const float* __restrict__ Wce, const float* __restrict__ Wse0,
                             const float* __restrict__ Wse1, const float* __restrict__ Wse3,
                             const float* __restrict__ Wdir, const float* __restrict__ Wpow,
                             const float* __restrict__ Wprop, char* __restrict__ wsb)
{
    __shared__ float s_wcd[32][32];
    __shared__ float s_wce[32][32];
    __shared__ float s_wsd[32][9];
    __shared__ float s_wse[32][4][9];
    __shared__ float s_wdir[4][32][4];
    const int tid = threadIdx.x;

    if (tid < 64) {
        int o = tid & 31;
        const float* src = (tid < 32) ? Wcd : Wce;
        float s = 0.f;
        for (int i = 0; i < 32; ++i) s += softplusf(src[o * 32 + i]);
        float inv = 1.f / s;
        for (int i = 0; i < 32; ++i) {
            float v = softplusf(src[o * 32 + i]) * inv;
            if (tid < 32) s_wcd[o][i] = v; else s_wce[o][i] = v;
        }
    }
    if (tid < 32) {
        int i = tid;
        float c0[3], c1[3]; float s = 0.f;
        for (int h = 0; h < 3; ++h) {
            c0[h] = softplusf(Wsd[(i * 3 + h) * 2 + 0]);
            c1[h] = softplusf(Wsd[(i * 3 + h) * 2 + 1]);
            s += 2.f * c0[h] + c1[h];
        }
        float inv = 1.f / s;
        for (int h = 0; h < 3; ++h) {
            s_wsd[i][h * 3 + 0] = c0[h] * inv;
            s_wsd[i][h * 3 + 1] = c1[h] * inv;
            s_wsd[i][h * 3 + 2] = c0[h] * inv;
        }
    }
    if (tid < 128) {
        int i = tid >> 2, d = tid & 3;
        float v[9];
        for (int h = 0; h < 3; ++h)
            for (int w = 0; w < 3; ++w) {
                float val;
                if (d == 0)      val = softplusf(Wse0[(i * 3 + h) * 3 + w]);
                else if (d == 1) val = softplusf(Wse1[(i * 3 + h) * 2 + (w == 1 ? 1 : 0)]);
                else if (d == 2) val = softplusf(Wse0[(i * 3 + h) * 3 + (2 - w)]);
                else             val = softplusf(Wse3[(i * 3 + h) * 2 + (w == 1 ? 1 : 0)]);
                v[h * 3 + w] = val;
            }
        float s = 0.f;
        for (int k = 0; k < 9; ++k) s += v[k];
        float inv = 1.f / s;
        for (int k = 0; k < 9; ++k) s_wse[i][d][k] = v[k] * inv;
    }
    if (tid < 128) {
        int p = tid >> 5, i = tid & 31;
        const int jmap[4][4] = {{0,1,2,3},{4,5,4,6},{2,1,0,3},{7,8,7,9}};
        float v[4]; float s = 0.f;
        for (int d = 0; d < 4; ++d) { v[d] = softplusf(Wdir[i * 10 + jmap[p][d]]); s += v[d]; }
        float inv = 1.f / s;
        for (int d = 0; d < 4; ++d) s_wdir[p][i][d] = v[d] * inv;
    }
    if (tid < 32) {
        int i = tid;
        float p0 = softplusf(Wpow[i*5+0]), p1 = softplusf(Wpow[i*5+1]), p2 = softplusf(Wpow[i*5+2]);
        float p3 = softplusf(Wpow[i*5+3]), p4 = softplusf(Wpow[i*5+4]);
        float* wp = (float*)(wsb + OFFB_WPOW) + (size_t)i * 8;
        wp[0]=p0; wp[1]=p2; wp[2]=p1; wp[3]=p4;   // s=0 (fwd)
        wp[4]=p1; wp[5]=p3; wp[6]=p0; wp[7]=p4;   // s=1 (bwd)
        float c0 = sigmf(Wprop[i*3+0]), c1 = sigmf(Wprop[i*3+1]), c2 = sigmf(Wprop[i*3+2]);
        float* pr = (float*)(wsb + OFFB_WPROP) + (size_t)i * 4;
        pr[0]=c1; pr[1]=c0; pr[2]=c1; pr[3]=c2;
    }
    __syncthreads();
    // conv_d weights in A-fragment bf16 layout: wdf[((tap*4+quad)*32+oc)*8+j], ic=quad*8+j
    unsigned short* wdf = (unsigned short*)(wsb + OFFB_WDFRAG);
    for (int idx = tid; idx < 9 * 4 * 32 * 8; idx += 256) {
        int j = idx & 7, oc = (idx >> 3) & 31, quad = (idx >> 8) & 3, tap = idx >> 10;
        int i = quad * 8 + j;
        wdf[idx] = f2bf(s_wcd[oc][i] * s_wsd[i][tap]);
    }
    // e-conv weights, bf16, A-fragment layout:
    unsigned short* wfrag = (unsigned short*)(wsb + OFFB_WFRAG);
    for (int idx = tid; idx < 9 * 16 * 128 * 8; idx += 256) {
        int j  = idx & 7;
        int oc = (idx >> 3) & 127;
        int qq = (idx >> 10) & 15;
        int tap = idx >> 14;
        int ic = qq * 8 + j;
        int o = oc >> 2, p = oc & 3, i = ic >> 2, d = ic & 3;
        float v = s_wce[o][i] * s_wdir[p][i][d] * s_wse[i][d][tap];
        wfrag[idx] = f2bf(v);
    }
}

// -------------------------------------------------------------- ce/ece in ---
__global__ __launch_bounds__(192) void prep_inputs(
    const float* __restrict__ xin, const float* __restrict__ ce,
    const float* __restrict__ ece, const char* __restrict__ wsb,
    unsigned short* __restrict__ ce_bf, unsigned short* __restrict__ ece_bf)
{
    const int x = threadIdx.x;      // 0..191
    const int y = blockIdx.x;       // 0..191
    const int i = blockIdx.y;       // 0..31
    const int b = blockIdx.z;       // 0..1
    const float* dcd = xin + ((size_t)(b * N + i)) * HW;
    const float* cd  = xin + ((size_t)((Bb + b) * N + i)) * HW;

    float cdv[3][3], dv[3][3];
    #pragma unroll
    for (int dy = -1; dy <= 1; ++dy)
        #pragma unroll
        for (int dx = -1; dx <= 1; ++dx) {
            int yy = y + dy, xx = x + dx;
            bool in = (yy >= 0 && yy < Hh && xx >= 0 && xx < Ww);
            float c = in ? cd[yy * Ww + xx] : 0.f;
            float dd = in ? dcd[yy * Ww + xx] : 0.f;
            cdv[dy + 1][dx + 1] = c;
            dv[dy + 1][dx + 1] = in ? dd * frcp(c + EPSF) : 0.f;
        }
    const float* wprop = (const float*)(wsb + OFFB_WPROP);
    const float* wpow  = (const float*)(wsb + OFFB_WPOW);
    const int oy[4] = {-1, -1, -1, 0}, ox[4] = {-1, 0, 1, 1};
    unsigned short cev[4], ecev[4];
    #pragma unroll
    for (int d = 0; d < 4; ++d) {
        float nf = dv[1 + oy[d]][1 + ox[d]];
        float df = dv[1 - oy[d]][1 - ox[d]];
        float rf = nf * frcp(df + EPSF);
        float rb = df * frcp(nf + EPSF);
        float p0 = wpow[i * 8 + d], p1 = wpow[i * 8 + 4 + d];
        float ef = fpow01(fminf(fmaxf(rf, EPSF), 1.f), p0);
        float eb = fpow01(fminf(fmaxf(rb, EPSF), 1.f), p1);
        float en = fminf(fmaxf(fminf(ef, eb), 0.f), 1.f);
        float cn = cdv[1 + oy[d]][1 + ox[d]] * cdv[1 - oy[d]][1 - ox[d]];
        float wp = wprop[i * 4 + d];
        size_t idx = ((size_t)(b * 128 + i * 4 + d)) * HW + (size_t)y * Ww + x;
        cev[d]  = f2bf(ce[idx] * wp + cn * (1.f - wp));
        ecev[d] = f2bf(ece[idx] * wp + en * cn * (1.f - wp));
    }
    size_t off = ((size_t)b * HW + (size_t)y * Ww + x) * 128 + i * 4;
    *(ushort4*)(ce_bf + off)  = make_ushort4(cev[0], cev[1], cev[2], cev[3]);
    *(ushort4*)(ece_bf + off) = make_ushort4(ecev[0], ecev[1], ecev[2], ecev[3]);
}

// ------------------------------------------- 128->128 3x3 conv via MFMA -----
__global__ __launch_bounds__(256) void conv_e_mfma(
    const unsigned short* __restrict__ ce_bf, const unsigned short* __restrict__ ece_bf,
    const unsigned short* __restrict__ wfrag,
    float* __restrict__ ce_out, float* __restrict__ ece_out)
{
    const int z = blockIdx.z; const int t = z >> 1; const int b = z & 1;
    const unsigned short* in_bf = (t ? ece_bf : ce_bf) + (size_t)b * HW * 128;
    float* outp = t ? ece_out : ce_out;

    __shared__ unsigned short tile[108 * 136];   // 29376 B

    const int tid  = threadIdx.x;
    const int lane = tid & 63;
    const int l16  = lane & 15;
    const int quad = lane >> 4;
    const int wave = tid >> 6;
    const int woc  = wave * 32;
    const int x0 = ((int)blockIdx.x % 12) * 16;
    const int y0 = ((int)blockIdx.x / 12) * 4;

    {
        const uint4* gsrc = (const uint4*)in_bf;
        for (int idx = tid; idx < 108 * 16; idx += 256) {
            int p = idx >> 4, c = idx & 15;
            int hy = p / 18, hx = p - hy * 18;
            int gy = y0 + hy - 1, gx = x0 + hx - 1;
            uint4 v = make_uint4(0u, 0u, 0u, 0u);
            if (gy >= 0 && gy < Hh && gx >= 0 && gx < Ww)
                v = gsrc[(size_t)(gy * Ww + gx) * 16 + c];
            *(uint4*)&tile[p * 136 + c * 8] = v;
        }
    }
    __syncthreads();

    f32x4 acc[2][4];
    #pragma unroll
    for (int mt = 0; mt < 2; ++mt)
        #pragma unroll
        for (int nt = 0; nt < 4; ++nt) acc[mt][nt] = (f32x4){0.f, 0.f, 0.f, 0.f};

    #pragma unroll
    for (int tap = 0; tap < 9; ++tap) {
        const int ky = tap / 3, kx = tap % 3;
        #pragma unroll
        for (int q = 0; q < 4; ++q) {
            const unsigned short* wb = wfrag + (size_t)((tap * 16 + q * 4 + quad) * 128) * 8;
            bf16x8 a0 = *(const bf16x8*)(wb + (woc + l16) * 8);
            bf16x8 a1 = *(const bf16x8*)(wb + (woc + 16 + l16) * 8);
            #pragma unroll
            for (int nt = 0; nt < 4; ++nt) {
                int p = (nt + ky) * 18 + (l16 + kx);
                bf16x8 bv = *(const bf16x8*)&tile[p * 136 + q * 32 + quad * 8];
                acc[0][nt] = __builtin_amdgcn_mfma_f32_16x16x32_bf16(a0, bv, acc[0][nt], 0, 0, 0);
                acc[1][nt] = __builtin_amdgcn_mfma_f32_16x16x32_bf16(a1, bv, acc[1][nt], 0, 0, 0);
            }
        }
    }

    #pragma unroll
    for (int mt = 0; mt < 2; ++mt)
        #pragma unroll
        for (int nt = 0; nt < 4; ++nt) {
            int y = y0 + nt, x = x0 + l16;
            #pragma unroll
            for (int r = 0; r < 4; ++r) {
                int oc = woc + mt * 16 + quad * 4 + r;
                outp[((size_t)b * 128 + oc) * HW + (size_t)y * Ww + x] = acc[mt][nt][r];
            }
        }
}

// ----------------------- gated 32->32 conv via MFMA (dcd_out & cd_out) ------
__global__ __launch_bounds__(256) void conv_d_mfma(
    const float* __restrict__ xin, const unsigned short* __restrict__ wdfrag,
    const float* __restrict__ ece_out, const float* __restrict__ ce_out,
    float* __restrict__ out0)
{
    const int b = blockIdx.y;
    __shared__ unsigned short xt[2][108 * 40];   // 17280 B
    __shared__ unsigned short Ebf[4 * 64 * 40];  // 20480 B

    const int tid  = threadIdx.x;
    const int lane = tid & 63;
    const int l16  = lane & 15;
    const int quad = lane >> 4;
    const int wave = tid >> 6;
    const int t    = wave >> 1;      // 0: dcd, 1: cd
    const int nh   = wave & 1;       // pixel half
    const int x0 = ((int)blockIdx.x % 12) * 16;
    const int y0 = ((int)blockIdx.x / 12) * 4;

    for (int idx = tid; idx < 2 * 32 * 108; idx += 256) {
        int hp = idx % 108;
        int r = idx / 108; int i = r & 31; int tt = r >> 5;
        int hy = hp / 18, hx = hp - hy * 18;
        int gy = y0 + hy - 1, gx = x0 + hx - 1;
        float v = 0.f;
        if (gy >= 0 && gy < Hh && gx >= 0 && gx < Ww)
            v = xin[((size_t)((tt * Bb + b) * N + i)) * HW + (size_t)gy * Ww + gx];
        xt[tt][hp * 40 + i] = f2bf(v);
    }
    for (int idx = tid; idx < 32 * 64; idx += 256) {
        int px = idx & 15, py = (idx >> 4) & 3, i = idx >> 6;
        size_t gp = (size_t)(y0 + py) * Ww + x0 + px;
        int p = py * 16 + px;
        #pragma unroll
        for (int d = 0; d < 4; ++d) {
            size_t eidx = ((size_t)(b * 128 + i * 4 + d)) * HW + gp;
            float e = fminf(fmaxf(ece_out[eidx] * frcp(ce_out[eidx] + EPSF), EPSF), 1.f);
            Ebf[(d * 64 + p) * 40 + i] = f2bf(e);
        }
    }
    __syncthreads();

    f32x4 acc[2][2];   // [ntile][mtile]
    #pragma unroll
    for (int nt = 0; nt < 2; ++nt)
        #pragma unroll
        for (int mt = 0; mt < 2; ++mt) acc[nt][mt] = (f32x4){0.f, 0.f, 0.f, 0.f};

    const int dmap[9] = {0, 1, 2, 3, 0, 3, 2, 1, 0};   // index 4 unused
    #pragma unroll
    for (int tap = 0; tap < 9; ++tap) {
        const int ky = tap / 3, kx = tap % 3;
        bf16x8 a0 = *(const bf16x8*)(wdfrag + (size_t)(((tap * 4 + quad) * 32) + l16) * 8);
        bf16x8 a1 = *(const bf16x8*)(wdfrag + (size_t)(((tap * 4 + quad) * 32) + 16 + l16) * 8);
        #pragma unroll
        for (int nt = 0; nt < 2; ++nt) {
            int p = nh * 32 + nt * 16 + l16;
            int py = p >> 4, px = p & 15;
            int hp = (py + ky) * 18 + px + kx;
            bf16x8 xv = *(const bf16x8*)&xt[t][hp * 40 + quad * 8];
            bf16x8 g;
            if (tap == 4) g = xv;
            else {
                bf16x8 ev = *(const bf16x8*)&Ebf[(dmap[tap] * 64 + p) * 40 + quad * 8];
                g = bfmul8(xv, ev);
            }
            acc[nt][0] = __builtin_amdgcn_mfma_f32_16x16x32_bf16(a0, g, acc[nt][0], 0, 0, 0);
            acc[nt][1] = __builtin_amdgcn_mfma_f32_16x16x32_bf16(a1, g, acc[nt][1], 0, 0, 0);
        }
    }

    #pragma unroll
    for (int nt = 0; nt < 2; ++nt) {
        int p = nh * 32 + nt * 16 + l16;
        int py = p >> 4, px = p & 15;
        size_t gp = (size_t)(y0 + py) * Ww + x0 + px;
        #pragma unroll
        for (int mt = 0; mt < 2; ++mt)
            #pragma unroll
            for (int r = 0; r < 4; ++r) {
                int oc = mt * 16 + quad * 4 + r;
                out0[((size_t)((t * Bb + b) * N + oc)) * HW + gp] = acc[nt][mt][r];
            }
    }
}

extern "C" void kernel_launch(void* const* d_in, const int* in_sizes, int n_in,
                              void* d_out, int out_size, void* d_ws, size_t ws_size,
                              hipStream_t stream)
{
    const float* x     = (const float*)d_in[0];
    const float* ece   = (const float*)d_in[1];
    const float* ce    = (const float*)d_in[2];
    const float* Wcd   = (const float*)d_in[3];
    const float* Wsd   = (const float*)d_in[4];
    const float* Wce   = (const float*)d_in[5];
    const float* Wse0  = (const float*)d_in[6];
    const float* Wse1  = (const float*)d_in[7];
    const float* Wse3  = (const float*)d_in[8];
    const float* Wdir  = (const float*)d_in[9];
    const float* Wpow  = (const float*)d_in[10];
    const float* Wprop = (const float*)d_in[11];
    float* out = (float*)d_out;
    char* wsb  = (char*)d_ws;

    unsigned short* ce_bf  = (unsigned short*)(wsb + OFFB_CE_BF);
    unsigned short* ece_bf = (unsigned short*)(wsb + OFFB_ECE_BF);
    unsigned short* wfrag  = (unsigned short*)(wsb + OFFB_WFRAG);
    unsigned short* wdfrag = (unsigned short*)(wsb + OFFB_WDFRAG);
    float* out0    = out;
    float* ece_out = out + OUT0_SZ;
    float* ce_out  = out + OUT0_SZ + EOUT_SZ;

    prep_weights<<<1, 256, 0, stream>>>(Wcd, Wsd, Wce, Wse0, Wse1, Wse3, Wdir, Wpow, Wprop, wsb);
    prep_inputs<<<dim3(Hh, N, Bb), 192, 0, stream>>>(x, ce, ece, wsb, ce_bf, ece_bf);
    conv_e_mfma<<<dim3(576, 1, 4), 256, 0, stream>>>(ce_bf, ece_bf, wfrag, ce_out, ece_out);
    conv_d_mfma<<<dim3(576, Bb), 256, 0, stream>>>(x, wdfrag, ece_out, ce_out, out0);
}